// Round 7
// baseline (253.313 us; speedup 1.0000x reference)
//
#include <hip/hip_runtime.h>
#include <hip/hip_bf16.h>
#include <cstdint>
#include <cstddef>

typedef __hip_bfloat16 bf16;
typedef __attribute__((ext_vector_type(8))) short short8;
typedef __attribute__((ext_vector_type(4))) short short4v;
typedef __attribute__((ext_vector_type(4))) float floatx4;

// Problem dims (all tensors float32; gates staged bf16)
#define BB 8
#define SS 4096
#define DIN 256
#define DH 512
#define NCH 256
#define CHUNK 16       // NCH*CHUNK == SS

__device__ __forceinline__ float b2f(bf16 v) { return __bfloat162float(v); }
__device__ __forceinline__ float sh2f(short v) {
    unsigned int u = ((unsigned int)(unsigned short)v) << 16;
    float f; __builtin_memcpy(&f, &u, 4); return f;
}
__device__ __forceinline__ float frcp(float x) { return __builtin_amdgcn_rcpf(x); }

// ---------------- kernel 0a: convert x tile (f32) -> Xb (bf16) ---------------
__global__ __launch_bounds__(256) void convert_x(
    const float* __restrict__ X, bf16* __restrict__ Xb)
{
    const int idx = blockIdx.x * 256 + threadIdx.x;
    float4 v = ((const float4*)X)[idx];
    bf16 o[4] = {__float2bfloat16(v.x), __float2bfloat16(v.y),
                 __float2bfloat16(v.z), __float2bfloat16(v.w)};
    ((short4v*)Xb)[idx] = *(const short4v*)o;
}

// ---------------- kernel 0b: W (f32 [256][512] x4) -> Wt (bf16 [2048][256]) --
__global__ __launch_bounds__(256) void transpose_w(
    const float* __restrict__ Wi, const float* __restrict__ Wf,
    const float* __restrict__ Wo, const float* __restrict__ Wz,
    bf16* __restrict__ Wt)
{
    int o  = blockIdx.x * 256 + threadIdx.x;
    int nf = o >> 8;
    int k  = o & 255;
    int g  = nf >> 9;
    int hh = nf & 511;
    const float* W = (g == 0) ? Wi : (g == 1) ? Wf : (g == 2) ? Wo : Wz;
    Wt[o] = __float2bfloat16(W[(size_t)k * DH + hh]);
}

// ---------------- kernel 1: fused GEMM + activation + chunk carries ----------
// Block: 64 m-rows (one s-chunk of 64 within batch b) x 256 n (4 gates x 64 h).
// Wave w computes gate w. Gates land in LDS (Gb), then: coalesced copy-out to
// planes + per-16-s affine carries (A,Bc,Bn) computed from LDS.
__device__ __forceinline__ void load16_lds(const bf16* g, short* l)
{
    __builtin_amdgcn_global_load_lds(
        (const __attribute__((address_space(1))) unsigned int*)g,
        (__attribute__((address_space(3))) unsigned int*)l,
        16, 0, 0);
}

__global__ __launch_bounds__(256) void gemm_fused(
    const bf16* __restrict__ Xb, const bf16* __restrict__ Wt,
    const float* __restrict__ bi, const float* __restrict__ bfv,
    const float* __restrict__ bo, const float* __restrict__ bz,
    bf16* __restrict__ Pi, bf16* __restrict__ Pf,
    bf16* __restrict__ Po, bf16* __restrict__ Pz,
    float* __restrict__ Aa, float* __restrict__ Bca, float* __restrict__ Bna,
    int nb)
{
    __shared__ __align__(16) short As[64 * 32];        // 4 KB
    __shared__ __align__(16) short Bs[256 * 32];       // 16 KB
    __shared__ __align__(16) bf16  Gb[4 * 64 * 64];    // 32 KB  [g][s][h]

    const int tid  = threadIdx.x;
    const int m0   = blockIdx.x * 64;        // row in pass (batch-aligned: 64|4096)
    const int h0   = blockIdx.y * 64;        // h band
    const int wave = tid >> 6, lane = tid & 63;
    const int l15  = lane & 15;
    const int q    = lane >> 4;

    floatx4 acc[4][4];
#pragma unroll
    for (int i = 0; i < 4; i++)
#pragma unroll
        for (int j = 0; j < 4; j++) acc[i][j] = (floatx4){0.f, 0.f, 0.f, 0.f};

    const int rr = tid >> 2;     // 0..63
    const int cc = (tid & 3) * 8;
    const bf16* agp = Xb + (size_t)(m0 + rr) * DIN + cc;
    const bf16* bgp0 = Wt + (size_t)(0 * 512 + h0 + rr) * DIN + cc;
    const bf16* bgp1 = Wt + (size_t)(1 * 512 + h0 + rr) * DIN + cc;
    const bf16* bgp2 = Wt + (size_t)(2 * 512 + h0 + rr) * DIN + cc;
    const bf16* bgp3 = Wt + (size_t)(3 * 512 + h0 + rr) * DIN + cc;

    for (int k0 = 0; k0 < DIN; k0 += 32) {
        load16_lds(agp + k0, &As[tid * 8]);
        load16_lds(bgp0 + k0, &Bs[0 * 2048 + tid * 8]);
        load16_lds(bgp1 + k0, &Bs[1 * 2048 + tid * 8]);
        load16_lds(bgp2 + k0, &Bs[2 * 2048 + tid * 8]);
        load16_lds(bgp3 + k0, &Bs[3 * 2048 + tid * 8]);
        __syncthreads();

        short8 af[4], bfr[4];
#pragma unroll
        for (int ti = 0; ti < 4; ti++)
            af[ti] = *(const short8*)&As[(ti * 16 + l15) * 32 + q * 8];
#pragma unroll
        for (int tj = 0; tj < 4; tj++)
            bfr[tj] = *(const short8*)&Bs[wave * 2048 + (tj * 16 + l15) * 32 + q * 8];
#pragma unroll
        for (int ti = 0; ti < 4; ti++)
#pragma unroll
            for (int tj = 0; tj < 4; tj++)
                acc[ti][tj] = __builtin_amdgcn_mfma_f32_16x16x32_bf16(
                    af[ti], bfr[tj], acc[ti][tj], 0, 0, 0);
        __syncthreads();
    }

    // ---- epilogue: activation -> Gb (LDS), gate = wave (wave-uniform) ----
    const float* bias = (wave == 0) ? bi : (wave == 1) ? bfv
                      : (wave == 2) ? bo : bz;
    bf16* gb = &Gb[wave * 4096];
#pragma unroll
    for (int ti = 0; ti < 4; ti++) {
#pragma unroll
        for (int tj = 0; tj < 4; tj++) {
            const int h = tj * 16 + l15;                 // local h 0..63
            const float bsv = bias[h0 + h];
#pragma unroll
            for (int r = 0; r < 4; r++) {
                const int s = ti * 16 + q * 4 + r;       // local s 0..63
                const float v = acc[ti][tj][r] + bsv;
                float a;
                if (wave == 0 || wave == 1)
                    a = __expf(fminf(fmaxf(v, -20.f), 0.f));      // exp(clip)
                else if (wave == 2)
                    a = frcp(1.f + __expf(-v));                   // sigmoid
                else
                    a = 1.f - 2.f * frcp(__expf(2.f * v) + 1.f);  // tanh
                gb[s * 64 + h] = __float2bfloat16(a);
            }
        }
    }
    __syncthreads();

    // ---- coalesced copy-out: Gb -> gate planes (16B/lane, full lines) ----
    bf16* const planes[4] = {Pi, Pf, Po, Pz};
#pragma unroll
    for (int p = 0; p < 8; p++) {
        const int cid = p * 256 + tid;      // 0..2047 chunks of 8 elems
        const int g   = cid >> 9;
        const int rem = cid & 511;
        const int s   = rem >> 3;
        const int c   = rem & 7;
        short8 v8 = *(const short8*)&Gb[g * 4096 + s * 64 + c * 8];
        *(short8*)&planes[g][(size_t)(m0 + s) * DH + h0 + c * 8] = v8;
    }

    // ---- fused chunk carries: 256 threads = 64 h x 4 sub-chunks of 16 ----
    {
        const int hh  = tid & 63;
        const int sub = tid >> 6;
        float A = 1.f, Bc = 0.f, Bn = 0.f;
#pragma unroll
        for (int s = 0; s < CHUNK; s++) {
            const int sl = sub * CHUNK + s;
            const float f  = b2f(Gb[1 * 4096 + sl * 64 + hh]);
            const float iv = b2f(Gb[0 * 4096 + sl * 64 + hh]);
            const float zv = b2f(Gb[3 * 4096 + sl * 64 + hh]);
            Bc = fmaf(f, Bc, iv * zv);
            Bn = fmaf(f, Bn, iv);
            A *= f;
        }
        const int b  = m0 >> 12;             // batch (SS = 4096)
        const int s0 = m0 & (SS - 1);
        const int ch = (s0 >> 4) + sub;      // global chunk-of-16 index
        const size_t cidx = ((size_t)ch * nb + b) * DH + h0 + hh;
        Aa[cidx] = A; Bca[cidx] = Bc; Bna[cidx] = Bn;
    }
}

// ---------------- kernel 3: sequential scan over chunk carries ---------------
__global__ __launch_bounds__(256) void scan_chunks(
    const float* __restrict__ Aa, const float* __restrict__ Bca,
    const float* __restrict__ Bna,
    float* __restrict__ Cs, float* __restrict__ Ns, int nb)
{
    const int t = blockIdx.x * 256 + threadIdx.x;   // b*512+h chain
    float c = 0.f, n = 1.f;
    for (int ch = 0; ch < NCH; ch++) {
        const size_t cidx = (size_t)ch * (nb * DH) + t;
        Cs[cidx] = c; Ns[cidx] = n;                 // state BEFORE chunk ch
        const float A = Aa[cidx];
        c = fmaf(A, c, Bca[cidx]);
        n = fmaf(A, n, Bna[cidx]);
    }
}

// ---------------- kernel 4: replay chunk with true init, emit h (f32) --------
__global__ __launch_bounds__(256) void scan_emit(
    const bf16* __restrict__ Pi, const bf16* __restrict__ Pf,
    const bf16* __restrict__ Po, const bf16* __restrict__ Pz,
    const float* __restrict__ Cs, const float* __restrict__ Ns,
    float* __restrict__ out, int nb)
{
    const int tid = threadIdx.x;
    const int ch  = blockIdx.x * 4 + (tid >> 6);
    const int b   = blockIdx.y;
    const int hg  = (tid & 63) * 8;
    const size_t base = ((size_t)(b * SS + ch * CHUNK)) * DH + hg;
    const size_t cidx = (size_t)(ch * nb + b) * DH + hg;

    float c[8], n[8];
#pragma unroll
    for (int j = 0; j < 2; j++) {
        *(floatx4*)&c[j * 4] = *(const floatx4*)(Cs + cidx + j * 4);
        *(floatx4*)&n[j * 4] = *(const floatx4*)(Ns + cidx + j * 4);
    }

#pragma unroll 4
    for (int s = 0; s < CHUNK; s++) {
        const size_t o = base + (size_t)s * DH;
        short8 i8 = *(const short8*)(Pi + o);
        short8 f8 = *(const short8*)(Pf + o);
        short8 o8 = *(const short8*)(Po + o);
        short8 z8 = *(const short8*)(Pz + o);
        float h[8];
#pragma unroll
        for (int j = 0; j < 8; j++) {
            const float f  = sh2f(f8[j]);
            const float iv = sh2f(i8[j]);
            const float ov = sh2f(o8[j]);
            const float zv = sh2f(z8[j]);
            c[j] = fmaf(f, c[j], iv * zv);
            n[j] = fmaf(f, n[j], iv);
            h[j] = ov * c[j] * frcp(n[j] + 1e-6f);
        }
        *(floatx4*)(out + o)     = *(floatx4*)&h[0];
        *(floatx4*)(out + o + 4) = *(floatx4*)&h[4];
    }
}

// ---------------- launch -----------------------------------------------------
extern "C" void kernel_launch(void* const* d_in, const int* in_sizes, int n_in,
                              void* d_out, int out_size, void* d_ws, size_t ws_size,
                              hipStream_t stream)
{
    const float* x   = (const float*)d_in[0];
    const float* Wi  = (const float*)d_in[1];
    const float* bi  = (const float*)d_in[2];
    const float* Wf  = (const float*)d_in[3];
    const float* bfv = (const float*)d_in[4];
    const float* Wo  = (const float*)d_in[5];
    const float* bo  = (const float*)d_in[6];
    const float* Wz  = (const float*)d_in[7];
    const float* bz  = (const float*)d_in[8];
    float* out = (float*)d_out;

    // ws-adaptive: nb batches per pass (~21.6 MB/batch + 1 MB; R4 proved ws>=201MB)
    int nb = BB;
    while (nb > 1) {
        size_t need = (1u << 20)                         // Wt
                    + (size_t)nb * SS * DIN * 2          // Xb
                    + 4 * (size_t)nb * SS * DH * 2       // Pi,Pf,Po,Pz
                    + 5 * (size_t)NCH * nb * DH * 4;     // Aa,Bca,Bna,Cs,Ns
        if (need <= ws_size) break;
        nb >>= 1;
    }

    const size_t plane = (size_t)nb * SS * DH;
    bf16* Wt = (bf16*)d_ws;
    bf16* Xb = (bf16*)((char*)d_ws + (1u << 20));
    bf16* Pi = Xb + (size_t)nb * SS * DIN;
    bf16* Pf = Pi + plane;
    bf16* Po = Pf + plane;
    bf16* Pz = Po + plane;
    float* Aa  = (float*)(Pz + plane);
    float* Bca = Aa  + (size_t)NCH * nb * DH;
    float* Bna = Bca + (size_t)NCH * nb * DH;
    float* Cs  = Bna + (size_t)NCH * nb * DH;
    float* Ns  = Cs  + (size_t)NCH * nb * DH;

    transpose_w<<<2048, 256, 0, stream>>>(Wi, Wf, Wo, Wz, Wt);

    for (int b0 = 0; b0 < BB; b0 += nb) {
        const float* Xsrc = x   + (size_t)b0 * SS * DIN;
        float*       Ob   = out + (size_t)b0 * SS * DH;
        convert_x<<<nb * 1024, 256, 0, stream>>>(Xsrc, Xb);
        gemm_fused<<<dim3(nb * SS / 64, DH / 64), 256, 0, stream>>>(
            Xb, Wt, bi, bfv, bo, bz, Pi, Pf, Po, Pz, Aa, Bca, Bna, nb);
        scan_chunks<<<2 * nb, 256, 0, stream>>>(Aa, Bca, Bna, Cs, Ns, nb);
        scan_emit<<<dim3(NCH / 4, nb), 256, 0, stream>>>(
            Pi, Pf, Po, Pz, Cs, Ns, Ob, nb);
    }
}